// Round 3
// baseline (173.892 us; speedup 1.0000x reference)
//
#include <hip/hip_runtime.h>

// StateSpaceDiffusionModel — MFMA formulation, round 5: producer/consumer pipeline.
//
// Scalar collapse (HW-verified):
//   r_t = u_t + sum_{j=0}^{63} w_j r_{t-1-j},   y_t = sum_{j=0}^{63} g_j r_{t-j}
// Chunked by 64, with S (IIR impulse-resp lower-tri Toeplitz), W (upper-tri),
// G1/G2 (g-tap Toeplitz):
//   c_m  = S·u_m                   (parallel over chunks)
//   p_{m+1} = A·p_m + c_m          (A = S·W dense; the ONLY serial part, 24 MFMA/chunk)
//   y_m  = G'·p_m + G2S·u_m        (G' = G1 + G2·A, G2S = G2·S; parallel given p_m)
// Round-2 lesson: ONE wave per head caps MFMA issue at ~1/19.4cy per SIMD
// (µbench 2075 TF = 4.85 cy/CU = 19.4 cy/SIMD) -> 3 of 4 SIMDs idle, MfmaUtil 15%.
// This round: 4 waves/block (one per SIMD), super-steps of SC=4 chunks:
//   wave0: serial recurrence for group s-1 (96 MFMA), publishes PRE-chunk states
//          as bf16 B-frags into a parity ring;
//   waves1-3: produce c[s] + yu[s]=G2S·u (held in regs) and finish
//          y[s-2] = yu + G'·p using the published states. Work split at
//          (chunk,mt)-tile granularity: tile t=4*cj+mt -> wave 1+(t%3).
// One lgkmcnt-only barrier per step (all cross-wave data in LDS; u loads and
// y stores stay in flight). 10 steps (8 groups + 2 pipeline fill/drain).
// Operators built in prologue by MFMA: A 4-term hi/lo, G'/G2S 3-term (same
// operator precision as before). Data path unchanged -> same absmax.
//
// mfma_f32_16x16x32_bf16 layouts (m89/m120):
//   A[m][k]: m=lane&15, k=(lane>>4)*8+j (+32*tk)
//   B[k][n]: k=(lane>>4)*8+j (+32*tk), n=lane&15
//   C[m][n]: n=lane&15, m=(lane>>4)*4+reg

namespace {

constexpr int kH = 512;
constexpr int kL = 2048;

typedef __attribute__((ext_vector_type(8))) short bf16x8;
typedef __attribute__((ext_vector_type(4))) float f32x4;

#define MFMA(A, B, C) __builtin_amdgcn_mfma_f32_16x16x32_bf16((A), (B), (C), 0, 0, 0)

__device__ inline unsigned int cvt_pk_bf16(float lo, float hi) {
  unsigned int r;
  asm("v_cvt_pk_bf16_f32 %0, %1, %2" : "=v"(r) : "v"(lo), "v"(hi));
  return r;
}

union B8U4 { bf16x8 v; unsigned int u[4]; };

// split 8 fp32 (two f32x4) into hi/lo bf16 fragments via packed RNE cvt
__device__ inline void cvt_split8(const f32x4 a, const f32x4 b, bf16x8& fh, bf16x8& fl) {
  B8U4 H, L;
  float x[8];
  #pragma unroll
  for (int j = 0; j < 4; ++j) { x[j] = a[j]; x[4 + j] = b[j]; }
  #pragma unroll
  for (int d = 0; d < 4; ++d) {
    const float x0 = x[2 * d], x1 = x[2 * d + 1];
    const unsigned int hp = cvt_pk_bf16(x0, x1);
    const float h0 = __uint_as_float(hp << 16);
    const float h1 = __uint_as_float(hp & 0xFFFF0000u);
    H.u[d] = hp;
    L.u[d] = cvt_pk_bf16(x0 - h0, x1 - h1);
  }
  fh = H.v; fl = L.v;
}

// Toeplitz A-operand fragment from a 128-tap array: value = tp[n0 - j]
__device__ inline void gen_frag(const float* tp, int n0, bf16x8& fh, bf16x8& fl) {
  float t[8];
  #pragma unroll
  for (int j = 0; j < 8; ++j) {
    const int n = n0 - j;
    t[j] = (n >= 0 && n < 127) ? tp[n] : 0.0f;
  }
  const f32x4 a = {t[0], t[1], t[2], t[3]};
  const f32x4 b = {t[4], t[5], t[6], t[7]};
  cvt_split8(a, b, fh, fl);
}

// Toeplitz B-operand fragment: value = tp[base + j]  (base in [0,119], no guard needed)
__device__ inline void gen_fragB(const float* tp, int base, bf16x8& fh, bf16x8& fl) {
  float t[8];
  #pragma unroll
  for (int j = 0; j < 8; ++j) t[j] = tp[base + j];
  const f32x4 a = {t[0], t[1], t[2], t[3]};
  const f32x4 b = {t[4], t[5], t[6], t[7]};
  cvt_split8(a, b, fh, fl);
}

// LDS pool layout (bytes), all offsets 16B-aligned. Total 123136 B -> 1 block/CU.
//   [     0, 34816) cring  f32[2][4][16][68]   (prologue alias: Astage f32[64][68] @0,
//                                               Pstage f32[64][68] @17408)
//   [ 34816, 67584) pring  bf16x8[2][4][4][64]
//   [ 67584, 83968) S_T    bf16x8[4][2][2][64]
//   [ 83968,100352) G2S_T  bf16x8[4][2][2][64]
//   [100352,116736) Gp_T   bf16x8[4][2][2][64]
//   [116736,121088) scratch f32[16][68]        (wave0 C->B round-trip)
//   [121088,122624) taps   f32[3][128]         (0=S pad, 1=G2 pad, 2=G1 pad)
//   [122624,123136) wPad   f32[128]

__global__ __launch_bounds__(256, 1)
void ssm_mfma_kernel(const float* __restrict__ u,
                     const float* __restrict__ kin,
                     float* __restrict__ y) {
  const int h    = blockIdx.x;
  const int tid  = threadIdx.x;
  const int wid  = tid >> 6;
  const int lane = tid & 63;
  const int ln16 = lane & 15;    // batch col (B/C) / row m (A)
  const int quad = lane >> 4;

  __shared__ alignas(16) char pool[123136];
  auto cring   = (float (*)[4][16][68]) (pool);
  auto Astage  = (float (*)[68]) (pool);
  auto Pstage  = (float (*)[68]) (pool + 17408);
  auto pring   = (bf16x8 (*)[4][4][64]) (pool + 34816);
  auto S_T     = (bf16x8 (*)[2][2][64]) (pool + 67584);
  auto G2S_T   = (bf16x8 (*)[2][2][64]) (pool + 83968);
  auto Gp_T    = (bf16x8 (*)[2][2][64]) (pool + 100352);
  auto scratch = (float (*)[68]) (pool + 116736);
  auto taps    = (float (*)[128]) (pool + 121088);
  float* wPad  = (float*) (pool + 122624);

  // ---------------- taps: wave0 shuffle scans (proven round-2 code) --------
  if (wid == 0) {
    const float kv = kin[h * 64 + lane];
    const float kc = fminf(fmaxf(kv, 0.0625f), 1.0f);
    float ks = kc;
    #pragma unroll
    for (int off = 32; off >= 1; off >>= 1) ks += __shfl_xor(ks, off);
    const float kn = kc / ks;
    const float cc = 1.0f / (1.0f + kn);
    float pp = cc;
    #pragma unroll
    for (int off = 1; off < 64; off <<= 1) {
      const float t = __shfl_up(pp, off);
      if (lane >= off) pp *= t;
    }
    float Pe = __shfl_up(pp, 1);
    if (lane == 0) Pe = 1.0f;
    const float wv = (lane < 63) ? (kn * cc * Pe) : Pe;
    const float gv = kv * Pe;
    float sv = (lane == 0) ? 1.0f : 0.0f;
    for (int rr = 0; rr < 63; ++rr) {
      const float s0 = __shfl(sv, rr);
      const float cf = __shfl(wv, lane - 1 - rr);
      if (lane > rr) sv = fmaf(cf, s0, sv);
    }
    taps[0][lane] = 0.0f;
    taps[1][lane] = 0.0f;
    const float gn = __shfl(gv, lane + 1);
    taps[2][lane] = (lane < 63) ? gn : 0.0f;  // G1: g[(i-j)+64]
    taps[2][64 + lane] = 0.0f;
    taps[0][63 + lane] = sv;                  // S: s[i-j]
    taps[1][63 + lane] = gv;                  // G2: g[i-j]
    if (lane == 0) { taps[0][127] = 0.0f; taps[1][127] = 0.0f; }
    wPad[lane] = wv;
    wPad[64 + lane] = 0.0f;
  }
  __syncthreads();

  // ---------------- prologue products: A = S·W (4-term), G2S = G2·S --------
  {
    const int mt = wid;
    bf16x8 xh[2], xl[2], g2h[2], g2l[2];
    #pragma unroll
    for (int tk = 0; tk < 2; ++tk) {
      const int n0 = 16 * mt + ln16 - (32 * tk + 8 * quad) + 63;
      gen_frag(taps[0], n0, xh[tk], xl[tk]);
      gen_frag(taps[1], n0, g2h[tk], g2l[tk]);
    }
    #pragma unroll
    for (int nt = 0; nt < 4; ++nt) {
      f32x4 accA = {0.f, 0.f, 0.f, 0.f};
      f32x4 accG = {0.f, 0.f, 0.f, 0.f};
      #pragma unroll
      for (int tk = 0; tk < 2; ++tk) {
        const int base = 8 * quad + 32 * tk - (16 * nt + ln16) + 63;
        bf16x8 bh, bl;
        gen_fragB(wPad, base, bh, bl);            // W as B: w[(k-n)+63]
        accA = MFMA(xh[tk], bh, accA);
        accA = MFMA(xh[tk], bl, accA);
        accA = MFMA(xl[tk], bh, accA);
        accA = MFMA(xl[tk], bl, accA);            // LL: A err ~2^-16
        bf16x8 sbh, sbl;
        gen_fragB(taps[0], base, sbh, sbl);       // S as B: s[k-n]
        accG = MFMA(g2h[tk], sbh, accG);
        accG = MFMA(g2h[tk], sbl, accG);
        accG = MFMA(g2l[tk], sbh, accG);
      }
      #pragma unroll
      for (int r = 0; r < 4; ++r) {
        Astage[16 * mt + 4 * quad + r][16 * nt + ln16] = accA[r];
        Pstage[16 * mt + 4 * quad + r][16 * nt + ln16] = accG[r];
      }
    }
  }
  __syncthreads();

  // ---------------- tables: S_T (from taps), G2S_T (from Pstage) -----------
  {
    const int mt = wid;
    #pragma unroll
    for (int tk = 0; tk < 2; ++tk) {
      const int n0 = 16 * mt + ln16 - (32 * tk + 8 * quad) + 63;
      bf16x8 fh, fl;
      gen_frag(taps[0], n0, fh, fl);
      S_T[mt][tk][0][lane] = fh;  S_T[mt][tk][1][lane] = fl;
      const int row = 16 * mt + ln16, k0 = 32 * tk + 8 * quad;
      const f32x4 a = *(const f32x4*)&Pstage[row][k0];
      const f32x4 b = *(const f32x4*)&Pstage[row][k0 + 4];
      cvt_split8(a, b, fh, fl);
      G2S_T[mt][tk][0][lane] = fh;  G2S_T[mt][tk][1][lane] = fl;
    }
  }
  __syncthreads();

  // ---------------- G' = G1 + G2·A -> Pstage (overwrites G2S stage) --------
  {
    const int mt = wid;
    bf16x8 g2h[2], g2l[2];
    #pragma unroll
    for (int tk = 0; tk < 2; ++tk) {
      const int n0 = 16 * mt + ln16 - (32 * tk + 8 * quad) + 63;
      gen_frag(taps[1], n0, g2h[tk], g2l[tk]);
    }
    #pragma unroll
    for (int nt = 0; nt < 4; ++nt) {
      f32x4 acc = {0.f, 0.f, 0.f, 0.f};
      #pragma unroll
      for (int tk = 0; tk < 2; ++tk) {
        float t[8];
        #pragma unroll
        for (int j = 0; j < 8; ++j)
          t[j] = Astage[8 * quad + 32 * tk + j][16 * nt + ln16];  // A as B (col reads)
        const f32x4 a = {t[0], t[1], t[2], t[3]};
        const f32x4 b = {t[4], t[5], t[6], t[7]};
        bf16x8 bh, bl;
        cvt_split8(a, b, bh, bl);
        acc = MFMA(g2h[tk], bh, acc);
        acc = MFMA(g2h[tk], bl, acc);
        acc = MFMA(g2l[tk], bh, acc);
      }
      #pragma unroll
      for (int r = 0; r < 4; ++r) {
        const int i = 16 * mt + 4 * quad + r, j = 16 * nt + ln16;
        Pstage[i][j] = acc[r] + taps[2][(i - j) + 63];            // + G1
      }
    }
  }
  __syncthreads();

  // ---------------- Gp_T table; wave0 A-fragments ---------------------------
  bf16x8 aH[4][2], aL[4][2];
  {
    const int mt = wid;
    #pragma unroll
    for (int tk = 0; tk < 2; ++tk) {
      const int row = 16 * mt + ln16, k0 = 32 * tk + 8 * quad;
      const f32x4 a = *(const f32x4*)&Pstage[row][k0];
      const f32x4 b = *(const f32x4*)&Pstage[row][k0 + 4];
      bf16x8 fh, fl;
      cvt_split8(a, b, fh, fl);
      Gp_T[mt][tk][0][lane] = fh;  Gp_T[mt][tk][1][lane] = fl;
    }
  }
  if (wid == 0) {
    #pragma unroll
    for (int mt = 0; mt < 4; ++mt) {
      #pragma unroll
      for (int tk = 0; tk < 2; ++tk) {
        const int row = 16 * mt + ln16, k0 = 32 * tk + 8 * quad;
        const f32x4 a = *(const f32x4*)&Astage[row][k0];
        const f32x4 b = *(const f32x4*)&Astage[row][k0 + 4];
        cvt_split8(a, b, aH[mt][tk], aL[mt][tk]);
      }
    }
  }
  __syncthreads();   // Astage/Pstage dead; cring (aliased) free for main loop

  // ---------------- main pipelined loop -------------------------------------
  bf16x8 pH[2], pL[2];
  {
    bf16x8 z;
    #pragma unroll
    for (int j = 0; j < 8; ++j) z[j] = 0;
    pH[0] = z; pH[1] = z; pL[0] = z; pL[1] = z;
  }

  const float* ub = u + ((size_t)ln16 * kH + h) * kL + 8 * quad;
  float* yb = y + ((size_t)ln16 * kH + h) * kL;

  f32x4 urC[4][4];                      // prefetched u, group s+1
  if (wid != 0) {
    #pragma unroll
    for (int cj = 0; cj < 4; ++cj)
      #pragma unroll
      for (int i = 0; i < 4; ++i)
        urC[cj][i] = *(const f32x4*)(ub + 64 * cj + 32 * (i >> 1) + 4 * (i & 1));
  }

  f32x4 yuE[6], yuO[6];                 // u-part of y, parity-split (rule #20)

  auto step = [&](int s, f32x4 (&yu)[6]) {
    if (wid == 0) {
      if (s >= 1 && s <= 8) {
        const int g = s - 1, gp = g & 1;
        for (int cj = 0; cj < 4; ++cj) {
          // publish PRE-chunk state p_{4g+cj} for consumers (y_m needs p_m)
          pring[gp][cj][0][lane] = pH[0];
          pring[gp][cj][1][lane] = pH[1];
          pring[gp][cj][2][lane] = pL[0];
          pring[gp][cj][3][lane] = pL[1];
          // r = A·p + c  (c as fp32 accumulator-init from ring)
          #pragma unroll
          for (int mt = 0; mt < 4; ++mt) {
            f32x4 acc = *(const f32x4*)&cring[gp][cj][ln16][16 * mt + 4 * quad];
            #pragma unroll
            for (int tk = 0; tk < 2; ++tk) {
              acc = MFMA(aH[mt][tk], pH[tk], acc);
              acc = MFMA(aH[mt][tk], pL[tk], acc);
              acc = MFMA(aL[mt][tk], pH[tk], acc);
            }
            *(f32x4*)&scratch[ln16][16 * mt + 4 * quad] = acc;
          }
          // C->B round-trip (intra-wave; DS pipe is in-order per wave)
          asm volatile("s_waitcnt lgkmcnt(0)" ::: "memory");
          __builtin_amdgcn_sched_barrier(0);
          #pragma unroll
          for (int tk = 0; tk < 2; ++tk) {
            const int k0 = 8 * quad + 32 * tk;
            const f32x4 ra = *(const f32x4*)&scratch[ln16][k0];
            const f32x4 rb = *(const f32x4*)&scratch[ln16][k0 + 4];
            cvt_split8(ra, rb, pH[tk], pL[tk]);   // new state
          }
        }
      }
    } else {
      // -------- consumers (wid 1..3) --------
      bf16x8 uH[4][2], uL[4][2];
      if (s < 8) {
        #pragma unroll
        for (int cj = 0; cj < 4; ++cj) {
          cvt_split8(urC[cj][0], urC[cj][1], uH[cj][0], uL[cj][0]);
          cvt_split8(urC[cj][2], urC[cj][3], uH[cj][1], uL[cj][1]);
        }
        if (s < 7) {
          #pragma unroll
          for (int cj = 0; cj < 4; ++cj)
            #pragma unroll
            for (int i = 0; i < 4; ++i)
              urC[cj][i] = *(const f32x4*)(ub + 64 * (4 * (s + 1) + cj) +
                                           32 * (i >> 1) + 4 * (i & 1));
        }
      }
      // finish y for group s-2 (reads yu BEFORE produce overwrites it)
      if (s >= 2) {
        const int gf = s - 2;
        #pragma unroll
        for (int cj = 0; cj < 4; ++cj) {
          bf16x8 pfH[2], pfL[2];
          pfH[0] = pring[s & 1][cj][0][lane];
          pfH[1] = pring[s & 1][cj][1][lane];
          pfL[0] = pring[s & 1][cj][2][lane];
          pfL[1] = pring[s & 1][cj][3][lane];
          #pragma unroll
          for (int mt = 0; mt < 4; ++mt) {
            const int t = 4 * cj + mt, li = t / 3;
            if ((t % 3) + 1 == wid) {
              f32x4 acc = yu[li];
              #pragma unroll
              for (int tk = 0; tk < 2; ++tk) {
                const bf16x8 gh = Gp_T[mt][tk][0][lane];
                const bf16x8 gl = Gp_T[mt][tk][1][lane];
                acc = MFMA(gh, pfH[tk], acc);
                acc = MFMA(gh, pfL[tk], acc);
                acc = MFMA(gl, pfH[tk], acc);
              }
              *(f32x4*)(yb + 64 * (4 * gf + cj) + 16 * mt + 4 * quad) = acc;
            }
          }
        }
      }
      // produce c[s] and yu[s]
      if (s < 8) {
        #pragma unroll
        for (int cj = 0; cj < 4; ++cj) {
          #pragma unroll
          for (int mt = 0; mt < 4; ++mt) {
            const int t = 4 * cj + mt, li = t / 3;
            if ((t % 3) + 1 == wid) {
              f32x4 accC = {0.f, 0.f, 0.f, 0.f};
              f32x4 accU = {0.f, 0.f, 0.f, 0.f};
              #pragma unroll
              for (int tk = 0; tk < 2; ++tk) {
                const bf16x8 sh = S_T[mt][tk][0][lane];
                const bf16x8 sl = S_T[mt][tk][1][lane];
                accC = MFMA(sh, uH[cj][tk], accC);
                accC = MFMA(sh, uL[cj][tk], accC);
                accC = MFMA(sl, uH[cj][tk], accC);
                const bf16x8 gh = G2S_T[mt][tk][0][lane];
                const bf16x8 gl = G2S_T[mt][tk][1][lane];
                accU = MFMA(gh, uH[cj][tk], accU);
                accU = MFMA(gh, uL[cj][tk], accU);
                accU = MFMA(gl, uH[cj][tk], accU);
              }
              *(f32x4*)&cring[s & 1][cj][ln16][16 * mt + 4 * quad] = accC;
              yu[li] = accU;
            }
          }
        }
      }
    }
    // step barrier: drain LDS writes only; global loads/stores stay in flight
    asm volatile("s_waitcnt lgkmcnt(0)" ::: "memory");
    __builtin_amdgcn_s_barrier();
    asm volatile("" ::: "memory");
  };

  #pragma unroll 1
  for (int sb = 0; sb < 5; ++sb) {
    step(2 * sb,     yuE);
    step(2 * sb + 1, yuO);
  }
}

}  // namespace

extern "C" void kernel_launch(void* const* d_in, const int* in_sizes, int n_in,
                              void* d_out, int out_size, void* d_ws, size_t ws_size,
                              hipStream_t stream) {
  const float* u  = (const float*)d_in[0];   // (16, 512, 2048) fp32
  const float* kk = (const float*)d_in[1];   // (1, 512, 64)    fp32
  if (n_in >= 2 && in_sizes[0] < in_sizes[1]) {
    const float* t = u; u = kk; kk = t;
  }
  float* yy = (float*)d_out;                 // (16, 512, 2048) fp32
  hipLaunchKernelGGL(ssm_mfma_kernel, dim3(kH), dim3(256), 0, stream, u, kk, yy);
}